// Round 3
// baseline (257.175 us; speedup 1.0000x reference)
//
#include <hip/hip_runtime.h>
#include <hip/hip_cooperative_groups.h>

namespace cg = cooperative_groups;

#define B_      4
#define N_      11
#define D_      589824L       // 64*96*96
#define NP2     66            // upper-tri incl diagonal (e2 pairs)
#define NP1     55            // strict upper-tri (e1 pairs; diag == 0)
#define TPB     256
#define CHUNKS  192           // blocks per batch -> grid 768 = exactly 3 blocks/CU
#define CFL     3072L         // floats per chunk = D_/CHUNKS
#define KW      12            // phase-1 per-wave iters: 64 lanes * 4 floats * 12 = 3072

typedef float nfloat4 __attribute__((ext_vector_type(4)));

// ---------------------------------------------------------------------------
// wave64 sum-reduction via DPP (pure VALU). Result valid in lane 63.
// (verbatim from rounds 1-2, correctness-proven)
// ---------------------------------------------------------------------------
__device__ __forceinline__ float wave_red_add(float x) {
    int t;
    t = __builtin_amdgcn_update_dpp(0, __float_as_int(x), 0x111, 0xf, 0xf, false); x += __int_as_float(t); // row_shr:1
    t = __builtin_amdgcn_update_dpp(0, __float_as_int(x), 0x112, 0xf, 0xf, false); x += __int_as_float(t); // row_shr:2
    t = __builtin_amdgcn_update_dpp(0, __float_as_int(x), 0x114, 0xf, 0xf, false); x += __int_as_float(t); // row_shr:4
    t = __builtin_amdgcn_update_dpp(0, __float_as_int(x), 0x118, 0xf, 0xf, false); x += __int_as_float(t); // row_shr:8
    t = __builtin_amdgcn_update_dpp(0, __float_as_int(x), 0x142, 0xa, 0xf, false); x += __int_as_float(t); // row_bcast:15
    t = __builtin_amdgcn_update_dpp(0, __float_as_int(x), 0x143, 0xc, 0xf, false); x += __int_as_float(t); // row_bcast:31
    return x;
}

__device__ __forceinline__ void loadrows(const float* __restrict__ xb, long d, float4 v[N_]) {
#pragma unroll
    for (int m = 0; m < N_; ++m)
        v[m] = *reinterpret_cast<const float4*>(xb + (long)m * D_ + d);
}

// accumulate dot-products for e2 pairs p in [P0,P1) (p enumerates i<=j)
template<int P0, int P1>
__device__ __forceinline__ void acc_e2(const float4 v[N_], float acc[P1 - P0]) {
    int p = 0;
#pragma unroll
    for (int i = 0; i < N_; ++i)
#pragma unroll
        for (int j = i; j < N_; ++j, ++p)
            if (p >= P0 && p < P1)
                acc[p - P0] += v[i].x * v[j].x + v[i].y * v[j].y +
                               v[i].z * v[j].z + v[i].w * v[j].w;
}

// accumulate L1 distances for e1 pairs p in [P0,P1) (p enumerates i<j)
template<int P0, int P1>
__device__ __forceinline__ void acc_e1(const float4 v[N_], float acc[P1 - P0]) {
    int p = 0;
#pragma unroll
    for (int i = 0; i < N_; ++i)
#pragma unroll
        for (int j = i + 1; j < N_; ++j, ++p)
            if (p >= P0 && p < P1)
                acc[p - P0] += fabsf(v[i].x - v[j].x) + fabsf(v[i].y - v[j].y) +
                               fabsf(v[i].z - v[j].z) + fabsf(v[i].w - v[j].w);
}

// ---------------------------------------------------------------------------
// Phase-1 wave body: 2-deep register ping-pong pipeline over KW iters.
// Loads for iter k+1 are issued BEFORE computing iter k -> compiler emits
// counted vmcnt (11 loads stay in flight through every compute burst).
// Each wave owns its pairs exclusively -> lane 63 atomics directly.
// ---------------------------------------------------------------------------
template<bool E2, int P0, int P1>
__device__ __forceinline__ void wave_body(const float* __restrict__ xb, long dbase,
                                          int lane, double* __restrict__ eb) {
    constexpr int NA = P1 - P0;
    float acc[NA];
#pragma unroll
    for (int p = 0; p < NA; ++p) acc[p] = 0.f;

    float4 va[N_], vb[N_];
    loadrows(xb, dbase, va);
#pragma unroll 1
    for (int k = 0; k < KW; k += 2) {
        loadrows(xb, dbase + (long)(k + 1) * 256, vb);
        if (E2) acc_e2<P0, P1>(va, acc); else acc_e1<P0, P1>(va, acc);
        if (k + 2 < KW) loadrows(xb, dbase + (long)(k + 2) * 256, va);
        if (E2) acc_e2<P0, P1>(vb, acc); else acc_e1<P0, P1>(vb, acc);
    }
#pragma unroll
    for (int p = 0; p < NA; ++p) {
        const float s = wave_red_add(acc[p]);
        if (lane == 63) atomicAdd(&eb[P0 + p], (double)s);
    }
}

__device__ __forceinline__ void pair_phase(const float* __restrict__ xb, long cbase, int t,
                                           double* __restrict__ e2b, double* __restrict__ e1b) {
    const int wave = t >> 6, lane = t & 63;
    const long dbase = cbase + (long)lane * 4;
    if      (wave == 0) wave_body<true,   0, 33>(xb, dbase, lane, e2b);
    else if (wave == 1) wave_body<true,  33, 66>(xb, dbase, lane, e2b);
    else if (wave == 2) wave_body<false,  0, 28>(xb, dbase, lane, e1b);
    else                wave_body<false, 28, 55>(xb, dbase, lane, e1b);
}

// ---------------------------------------------------------------------------
// Phase 2: E = e1*e2 (symmetric, diag 0); M = gamma*softmax(max-E) + I.
// (verbatim from round 2, correctness-proven)
// ---------------------------------------------------------------------------
__device__ __forceinline__ void build_M(const double* __restrict__ e2b,
                                        const double* __restrict__ e1b,
                                        const float* __restrict__ gamma,
                                        int t, float* __restrict__ M) {
    __shared__ double E[N_][N_];
    if (t < NP2) {
        int rem = t, i = 0, cnt = N_;
        while (rem >= cnt) { rem -= cnt; --cnt; ++i; }
        const int j = i + rem;
        double e = 0.0;
        if (j > i) {
            const int q = i * (2 * N_ - 1 - i) / 2 + (j - i - 1);
            e = e1b[q] * e2b[t];
        }
        E[i][j] = e;
        E[j][i] = e;
    }
    __syncthreads();
    if (t < N_) {
        const int i = t;
        double mn = E[i][0];
#pragma unroll
        for (int j = 1; j < N_; ++j) mn = fmin(mn, E[i][j]);
        double ex[N_], s = 0.0;
#pragma unroll
        for (int j = 0; j < N_; ++j) { ex[j] = exp(mn - E[i][j]); s += ex[j]; }
        const float g = gamma[0];
        const double inv = 1.0 / s;
#pragma unroll
        for (int j = 0; j < N_; ++j)
            M[i * N_ + j] = (float)(ex[j] * inv) * g + (i == j ? 1.0f : 0.0f);
    }
}

// ---------------------------------------------------------------------------
// Phase 3: out[n,d] = sum_m M[n][m] * x[m,d], 2-deep pipelined over 3 iters.
// n-loop kept runtime so M stays in LDS (broadcast reads, no reg blowup).
// ---------------------------------------------------------------------------
__device__ __forceinline__ void mat_rows(const float4 v[N_], const float* __restrict__ M,
                                         float* __restrict__ ob, long d) {
#pragma unroll 1
    for (int n = 0; n < N_; ++n) {
        float4 o = make_float4(0.f, 0.f, 0.f, 0.f);
#pragma unroll
        for (int m = 0; m < N_; ++m) {
            const float w = M[n * N_ + m];
            o.x += w * v[m].x; o.y += w * v[m].y;
            o.z += w * v[m].z; o.w += w * v[m].w;
        }
        union { float4 f; nfloat4 n4; } u;
        u.f = o;
        __builtin_nontemporal_store(u.n4, reinterpret_cast<nfloat4*>(ob + (long)n * D_ + d));
    }
}

__device__ __forceinline__ void apply_phase(const float* __restrict__ xb, float* __restrict__ ob,
                                            long cbase, int t, const float* __restrict__ M) {
    const long d0 = cbase + (long)t * 4;     // 256 threads * 4 floats = 1024/iter, 3 iters
    float4 a[N_], b[N_];
    loadrows(xb, d0, a);
    loadrows(xb, d0 + 1024, b);
    mat_rows(a, M, ob, d0);
    loadrows(xb, d0 + 2048, a);
    mat_rows(b, M, ob, d0 + 1024);
    mat_rows(a, M, ob, d0 + 2048);
}

// ---------------------------------------------------------------------------
// Fused cooperative kernel: reduce -> grid.sync -> softmax -> apply.
// ---------------------------------------------------------------------------
__global__ __launch_bounds__(TPB) void fused_kernel(const float* __restrict__ x,
                                                    const float* __restrict__ gamma,
                                                    double* __restrict__ e2ws,
                                                    double* __restrict__ e1ws,
                                                    float* __restrict__ out) {
    const int b = blockIdx.y, chunk = blockIdx.x, t = threadIdx.x;
    const float* xb = x + (long)b * N_ * D_;
    const long cbase = (long)chunk * CFL;

    pair_phase(xb, cbase, t, e2ws + b * NP2, e1ws + b * NP1);

    cg::this_grid().sync();

    __shared__ float M[N_ * N_];
    build_M(e2ws + b * NP2, e1ws + b * NP1, gamma, t, M);
    __syncthreads();

    apply_phase(xb, out + (long)b * N_ * D_, cbase, t, M);
}

// ---------------------------------------------------------------------------
// Fallback path (same bodies, 3 launches) if residency < 3 blocks/CU.
// ---------------------------------------------------------------------------
__global__ __launch_bounds__(TPB) void reduce_kernel(const float* __restrict__ x,
                                                     double* __restrict__ e2ws,
                                                     double* __restrict__ e1ws) {
    const int b = blockIdx.y, chunk = blockIdx.x, t = threadIdx.x;
    pair_phase(x + (long)b * N_ * D_, (long)chunk * CFL, t, e2ws + b * NP2, e1ws + b * NP1);
}

__global__ __launch_bounds__(128) void attn_kernel(const double* __restrict__ e2ws,
                                                   const double* __restrict__ e1ws,
                                                   const float* __restrict__ gamma,
                                                   float* __restrict__ Mws) {
    const int b = blockIdx.x, t = threadIdx.x;
    __shared__ float M[N_ * N_];
    build_M(e2ws + b * NP2, e1ws + b * NP1, gamma, t, M);
    __syncthreads();
    if (t < N_ * N_) Mws[b * N_ * N_ + t] = M[t];
}

__global__ __launch_bounds__(TPB) void apply_kernel(const float* __restrict__ x,
                                                    const float* __restrict__ Mws,
                                                    float* __restrict__ out) {
    const int b = blockIdx.y, chunk = blockIdx.x, t = threadIdx.x;
    __shared__ float M[N_ * N_];
    if (t < N_ * N_) M[t] = Mws[b * N_ * N_ + t];
    __syncthreads();
    apply_phase(x + (long)b * N_ * D_, out + (long)b * N_ * D_, (long)chunk * CFL, t, M);
}

// ---------------------------------------------------------------------------
extern "C" void kernel_launch(void* const* d_in, const int* in_sizes, int n_in,
                              void* d_out, int out_size, void* d_ws, size_t ws_size,
                              hipStream_t stream) {
    const float* x     = (const float*)d_in[0];
    const float* gamma = (const float*)d_in[1];
    float* out         = (float*)d_out;

    double* e2ws = (double*)d_ws;                // B_*NP2 doubles
    double* e1ws = e2ws + B_ * NP2;              // B_*NP1 doubles
    float*  Mws  = (float*)(e1ws + B_ * NP1);    // fallback only

    // zero fp64 accumulators (ws is poisoned before every launch)
    hipMemsetAsync(d_ws, 0, (size_t)(B_ * (NP2 + NP1)) * sizeof(double), stream);

    static int coop = -1;
    if (coop < 0) {
        int nb = 0;
        if (hipOccupancyMaxActiveBlocksPerMultiprocessor(&nb, fused_kernel, TPB, 0) != hipSuccess)
            nb = 0;
        coop = (nb >= 3) ? 1 : 0;   // need all 768 blocks co-resident (3/CU)
    }

    dim3 grid(CHUNKS, B_);
    if (coop) {
        void* args[] = {(void*)&x, (void*)&gamma, (void*)&e2ws, (void*)&e1ws, (void*)&out};
        hipLaunchCooperativeKernel((void*)fused_kernel, grid, dim3(TPB), args, 0, stream);
    } else {
        reduce_kernel<<<grid, TPB, 0, stream>>>(x, e2ws, e1ws);
        attn_kernel<<<B_, 128, 0, stream>>>(e2ws, e1ws, gamma, Mws);
        apply_kernel<<<grid, TPB, 0, stream>>>(x, Mws, out);
    }
}

// Round 4
// 225.129 us; speedup vs baseline: 1.1423x; 1.1423x over previous
//
#include <hip/hip_runtime.h>

#define B_    4
#define N_    11
#define D_    589824L     // 64*96*96
#define NP2   66          // upper-tri incl diagonal (e2 pairs)
#define NP1   55          // strict upper-tri (e1 pairs)
#define GX    128         // chunks per batch -> grid (128,4) = 512 blocks = 2/CU
#define CPB   4608L       // floats per chunk = D_/GX
#define TILE  512         // floats per row per tile
#define NT    9           // tiles per chunk = CPB/TILE
#define TPB   256         // 4 waves

typedef float nfloat2 __attribute__((ext_vector_type(2)));

// async global->LDS DMA, 16B/lane; LDS dest is WAVE-UNIFORM base (+lane*16 implicit)
#define GLD16(g, l) __builtin_amdgcn_global_load_lds(                      \
    (const __attribute__((address_space(1))) void*)(g),                    \
    (__attribute__((address_space(3))) void*)(l), 16, 0, 0)

// ---------------------------------------------------------------------------
// wave64 sum-reduction via DPP (pure VALU). Result valid in lane 63. (proven r1-r3)
// ---------------------------------------------------------------------------
__device__ __forceinline__ float wave_red_add(float x) {
    int t;
    t = __builtin_amdgcn_update_dpp(0, __float_as_int(x), 0x111, 0xf, 0xf, false); x += __int_as_float(t);
    t = __builtin_amdgcn_update_dpp(0, __float_as_int(x), 0x112, 0xf, 0xf, false); x += __int_as_float(t);
    t = __builtin_amdgcn_update_dpp(0, __float_as_int(x), 0x114, 0xf, 0xf, false); x += __int_as_float(t);
    t = __builtin_amdgcn_update_dpp(0, __float_as_int(x), 0x118, 0xf, 0xf, false); x += __int_as_float(t);
    t = __builtin_amdgcn_update_dpp(0, __float_as_int(x), 0x142, 0xa, 0xf, false); x += __int_as_float(t);
    t = __builtin_amdgcn_update_dpp(0, __float_as_int(x), 0x143, 0xc, 0xf, false); x += __int_as_float(t);
    return x;
}

// ---------------------------------------------------------------------------
// Stage one tile (11 rows x TILE floats) into LDS: 22 sections of 256 floats;
// wave w issues sections s%4==w (w0/w1: 6, w2/w3: 5). Per-wave in-flight
// tracked by vmcnt; conservative waits use min section count (5).
// ---------------------------------------------------------------------------
__device__ __forceinline__ void stage_tile(const float* __restrict__ xb, long tbase,
                                           float* __restrict__ dst, int wave, int lane) {
#pragma unroll 1
    for (int s = wave; s < 22; s += 4) {
        const int r = s >> 1, h = s & 1;
        GLD16(xb + (long)r * D_ + tbase + h * 256 + lane * 4,
              dst + r * TILE + h * 256);
    }
}

// ---------------------------------------------------------------------------
// K1 per-wave body: NB2 e2-pairs starting at A2, NB1 e1-pairs starting at A1.
// Double-buffered async pipeline; counted vmcnt; raw s_barrier (no drain).
// ---------------------------------------------------------------------------
template<int A2, int NB2, int A1, int NB1>
__device__ __forceinline__ void k1_wave(const float* __restrict__ xb, long tb0,
                                        int wave, int lane,
                                        float (*buf)[N_ * TILE],
                                        double* __restrict__ e2b,
                                        double* __restrict__ e1b) {
    float acc2[NB2 ? NB2 : 1];
    float acc1[NB1 ? NB1 : 1];
#pragma unroll
    for (int p = 0; p < (NB2 ? NB2 : 1); ++p) acc2[p] = 0.f;
#pragma unroll
    for (int p = 0; p < (NB1 ? NB1 : 1); ++p) acc1[p] = 0.f;

    stage_tile(xb, tb0, buf[0], wave, lane);
    stage_tile(xb, tb0 + TILE, buf[1], wave, lane);

#pragma unroll 1
    for (int k = 0; k < NT; ++k) {
        // own stage(k) sections done (in-order vmcnt retirement; <=5 allows next tile in flight)
        if (k + 1 < NT) asm volatile("s_waitcnt vmcnt(5)" ::: "memory");
        else            asm volatile("s_waitcnt vmcnt(0)" ::: "memory");
        __builtin_amdgcn_s_barrier();          // all waves' stage(k) done
        asm volatile("" ::: "memory");
        const float* bT = buf[k & 1];
#pragma unroll
        for (int g = 0; g < 2; ++g) {
            float4 v[N_];
#pragma unroll
            for (int r = 0; r < N_; ++r)
                v[r] = *reinterpret_cast<const float4*>(bT + r * TILE + g * 256 + lane * 4);
            if constexpr (NB2 > 0) {
                int p = 0;
#pragma unroll
                for (int i = 0; i < N_; ++i)
#pragma unroll
                    for (int j = i; j < N_; ++j, ++p)
                        if (p >= A2 && p < A2 + NB2)
                            acc2[p - A2] += v[i].x * v[j].x + v[i].y * v[j].y +
                                            v[i].z * v[j].z + v[i].w * v[j].w;
            }
            if constexpr (NB1 > 0) {
                int q = 0;
#pragma unroll
                for (int i = 0; i < N_; ++i)
#pragma unroll
                    for (int j = i + 1; j < N_; ++j, ++q)
                        if (q >= A1 && q < A1 + NB1)
                            acc1[q - A1] += fabsf(v[i].x - v[j].x) + fabsf(v[i].y - v[j].y) +
                                            fabsf(v[i].z - v[j].z) + fabsf(v[i].w - v[j].w);
            }
        }
        asm volatile("" ::: "memory");
        __builtin_amdgcn_s_barrier();          // all waves done reading buf[k&1]
        asm volatile("" ::: "memory");
        if (k + 2 < NT) stage_tile(xb, tb0 + (long)(k + 2) * TILE, buf[k & 1], wave, lane);
    }

    if constexpr (NB2 > 0) {
#pragma unroll
        for (int p = 0; p < NB2; ++p) {
            const float s = wave_red_add(acc2[p]);
            if (lane == 63) atomicAdd(&e2b[A2 + p], (double)s);
        }
    }
    if constexpr (NB1 > 0) {
#pragma unroll
        for (int p = 0; p < NB1; ++p) {
            const float s = wave_red_add(acc1[p]);
            if (lane == 63) atomicAdd(&e1b[A1 + p], (double)s);
        }
    }
}

// ---------------------------------------------------------------------------
// K1: balanced 4-wave split (VALU cost units: 172/172/176/184)
// ---------------------------------------------------------------------------
__global__ __launch_bounds__(TPB) void reduce_kernel(const float* __restrict__ x,
                                                     double* __restrict__ e2ws,
                                                     double* __restrict__ e1ws) {
    const int b = blockIdx.y, c = blockIdx.x, t = threadIdx.x;
    const int wave = t >> 6, lane = t & 63;
    const float* xb = x + (long)b * N_ * D_;
    const long tb0 = (long)c * CPB;
    __shared__ float buf[2][N_ * TILE];   // 44 KB
    double* e2b = e2ws + b * NP2;
    double* e1b = e1ws + b * NP1;

    if      (wave == 0) k1_wave< 0, 33,  0,  5>(xb, tb0, wave, lane, buf, e2b, e1b);
    else if (wave == 1) k1_wave<33, 33,  5,  5>(xb, tb0, wave, lane, buf, e2b, e1b);
    else if (wave == 2) k1_wave< 0,  0, 10, 22>(xb, tb0, wave, lane, buf, e2b, e1b);
    else                k1_wave< 0,  0, 32, 23>(xb, tb0, wave, lane, buf, e2b, e1b);
}

// ---------------------------------------------------------------------------
// K2: E = e1*e2 (symmetric, diag 0); M = gamma*softmax(max-E) + I. (proven r0-r3)
// ---------------------------------------------------------------------------
__global__ __launch_bounds__(128) void attn_kernel(const double* __restrict__ e2ws,
                                                   const double* __restrict__ e1ws,
                                                   const float* __restrict__ gamma,
                                                   float* __restrict__ Mws) {
    const int b = blockIdx.x, t = threadIdx.x;
    __shared__ double E[N_][N_];
    if (t < NP2) {
        int rem = t, i = 0, cnt = N_;
        while (rem >= cnt) { rem -= cnt; --cnt; ++i; }
        const int j = i + rem;
        double e = 0.0;
        if (j > i) {
            const int q = i * (2 * N_ - 1 - i) / 2 + (j - i - 1);
            e = e1ws[b * NP1 + q] * e2ws[b * NP2 + t];
        }
        E[i][j] = e;
        E[j][i] = e;
    }
    __syncthreads();
    if (t < N_) {
        const int i = t;
        double mn = E[i][0];
#pragma unroll
        for (int j = 1; j < N_; ++j) mn = fmin(mn, E[i][j]);
        double ex[N_], s = 0.0;
#pragma unroll
        for (int j = 0; j < N_; ++j) { ex[j] = exp(mn - E[i][j]); s += ex[j]; }
        const float g = gamma[0];
        const double inv = 1.0 / s;
#pragma unroll
        for (int j = 0; j < N_; ++j)
            Mws[(b * N_ + i) * N_ + j] = (float)(ex[j] * inv) * g + (i == j ? 1.0f : 0.0f);
    }
}

// ---------------------------------------------------------------------------
// K3: out[n,d] = sum_m M[n][m]*x[m,d]; LDS-staged async pipeline; NT stores
// per thread per tile (nontemporal, fire-and-forget). x is L3-hot from K1.
// Per-wave vmcnt: k==0 -> 5 ; mid -> 16 (= 11 stores + >=5 stage) ; last -> 11.
// ---------------------------------------------------------------------------
__global__ __launch_bounds__(TPB) void apply_kernel(const float* __restrict__ x,
                                                    const float* __restrict__ Mws,
                                                    float* __restrict__ out) {
    const int b = blockIdx.y, c = blockIdx.x, t = threadIdx.x;
    const int wave = t >> 6, lane = t & 63;
    const float* xb = x + (long)b * N_ * D_;
    float* ob = out + (long)b * N_ * D_;
    const long tb0 = (long)c * CPB;
    __shared__ float buf[2][N_ * TILE];   // 44 KB
    __shared__ float M[N_ * N_];

    if (t < N_ * N_) M[t] = Mws[b * N_ * N_ + t];
    __syncthreads();   // full drain: clean per-wave vmcnt before the pipeline

    stage_tile(xb, tb0, buf[0], wave, lane);
    stage_tile(xb, tb0 + TILE, buf[1], wave, lane);

#pragma unroll 1
    for (int k = 0; k < NT; ++k) {
        if      (k == 0)     asm volatile("s_waitcnt vmcnt(5)"  ::: "memory");
        else if (k < NT - 1) asm volatile("s_waitcnt vmcnt(16)" ::: "memory");
        else                 asm volatile("s_waitcnt vmcnt(11)" ::: "memory");
        __builtin_amdgcn_s_barrier();
        asm volatile("" ::: "memory");

        const float* bT = buf[k & 1];
        float vx[N_], vy[N_];
#pragma unroll
        for (int r = 0; r < N_; ++r) {
            const float2 vv = *reinterpret_cast<const float2*>(bT + r * TILE + t * 2);
            vx[r] = vv.x; vy[r] = vv.y;
        }
        const long dd = tb0 + (long)k * TILE + t * 2;
#pragma unroll
        for (int n = 0; n < N_; ++n) {
            float ox = 0.f, oy = 0.f;
#pragma unroll
            for (int m = 0; m < N_; ++m) {
                const float w = M[n * N_ + m];
                ox += w * vx[m]; oy += w * vy[m];
            }
            nfloat2 o; o[0] = ox; o[1] = oy;
            __builtin_nontemporal_store(o, reinterpret_cast<nfloat2*>(ob + (long)n * D_ + dd));
        }

        asm volatile("" ::: "memory");
        __builtin_amdgcn_s_barrier();
        asm volatile("" ::: "memory");
        if (k + 2 < NT) stage_tile(xb, tb0 + (long)(k + 2) * TILE, buf[k & 1], wave, lane);
    }
}

// ---------------------------------------------------------------------------
extern "C" void kernel_launch(void* const* d_in, const int* in_sizes, int n_in,
                              void* d_out, int out_size, void* d_ws, size_t ws_size,
                              hipStream_t stream) {
    const float* x     = (const float*)d_in[0];
    const float* gamma = (const float*)d_in[1];
    float* out         = (float*)d_out;

    double* e2ws = (double*)d_ws;                // B_*NP2 doubles
    double* e1ws = e2ws + B_ * NP2;              // B_*NP1 doubles
    float*  Mws  = (float*)(e1ws + B_ * NP1);    // B_*121 floats

    // zero fp64 accumulators (ws is poisoned before every launch)
    hipMemsetAsync(d_ws, 0, (size_t)(B_ * (NP2 + NP1)) * sizeof(double), stream);

    dim3 grid(GX, B_);                           // (128,4) = 512 blocks = 2/CU
    reduce_kernel<<<grid, TPB, 0, stream>>>(x, e2ws, e1ws);
    attn_kernel<<<B_, 128, 0, stream>>>(e2ws, e1ws, gamma, Mws);
    apply_kernel<<<grid, TPB, 0, stream>>>(x, Mws, out);
}